// Round 1
// baseline (2635.736 us; speedup 1.0000x reference)
//
#include <hip/hip_runtime.h>

typedef __attribute__((ext_vector_type(8))) short bf16x8;
typedef __attribute__((ext_vector_type(4))) float f32x4;

#define T_ 1024

// round-to-nearest-even f32 -> bf16 bits
__device__ __forceinline__ unsigned short f2bf(float f) {
  unsigned int u = __float_as_uint(f);
  u += 0x7fffu + ((u >> 16) & 1u);
  return (unsigned short)(u >> 16);
}

// tanh(x) = 1 - 2/(1+e^{2x}); e=inf -> 1, e=0 -> -1 (no NaN for finite x)
__device__ __forceinline__ float tanh_fast(float x) {
  float e = __expf(2.0f * x);
  return 1.0f - __fdividef(2.0f, 1.0f + e);
}

// ---- x (fp32) -> bf16, vectorized float4 -> ushort4 ----
__global__ __launch_bounds__(256) void k_cvt_x(const float* __restrict__ x,
                                               unsigned short* __restrict__ o,
                                               int n4) {
  int i = blockIdx.x * 256 + threadIdx.x;
  if (i >= n4) return;
  float4 v = ((const float4*)x)[i];
  ushort4 r;
  r.x = f2bf(v.x); r.y = f2bf(v.y); r.z = f2bf(v.z); r.w = f2bf(v.w);
  *(ushort4*)(o + 4 * (size_t)i) = r;
}

// ---- weight [256][256] fp32 -> transposed bf16 [n][k] (k-contiguous for B-frags) ----
__global__ __launch_bounds__(256) void k_cvt_t(const float* __restrict__ w,
                                               unsigned short* __restrict__ wt) {
  int f = blockIdx.x, u = threadIdx.x;
  wt[u * 256 + f] = f2bf(w[f * 256 + u]);
}

// ---- C[M x 256] = A(bf16,[M x 256]) @ B(via Bt=B^T bf16 [256][256]) + bias ----
// WG = 256 thr (4 waves), one 16-row M-tile per WG, wave w covers cols [64w,64w+64)
// Fragment maps (mfma_f32_16x16x32_bf16):
//   A: lane l -> row l&15,  k = 8*(l>>4)+j   (8 contiguous bf16 = 1 dwordx4)
//   B: lane l -> col l&15,  k = 8*(l>>4)+j   (read from Bt[n][k], contiguous)
//   D: lane l -> col l&15,  row = 4*(l>>4)+j (m89-verified)
__global__ __launch_bounds__(256) void k_gemm(const unsigned short* __restrict__ A,
                                              const unsigned short* __restrict__ Bt,
                                              const float* __restrict__ bias,
                                              float* __restrict__ C, int M) {
  const int wave = threadIdx.x >> 6, lane = threadIdx.x & 63;
  const int lo = lane & 15, hi = lane >> 4;
  const size_t mt = blockIdx.x;
  const unsigned short* Ap = A + (mt * 16 + lo) * 256 + hi * 8;
  bf16x8 a[8];
#pragma unroll
  for (int kt = 0; kt < 8; ++kt) a[kt] = *(const bf16x8*)(Ap + kt * 32);
#pragma unroll
  for (int nt = 0; nt < 4; ++nt) {
    const int n = wave * 64 + nt * 16 + lo;
    const unsigned short* Bp = Bt + (size_t)n * 256 + hi * 8;
    const float bv = bias[n];
    f32x4 acc = {bv, bv, bv, bv};
#pragma unroll
    for (int kt = 0; kt < 8; ++kt) {
      bf16x8 b = *(const bf16x8*)(Bp + kt * 32);
      acc = __builtin_amdgcn_mfma_f32_16x16x32_bf16(a[kt], b, acc, 0, 0, 0);
    }
    float* Cp = C + (mt * 16 + hi * 4) * 256 + n;
#pragma unroll
    for (int j = 0; j < 4; ++j) Cp[j * 256] = acc[j];
  }
}

// ---- recurrent scan: h_t = tanh(xp[b,t,:] + h_{t-1} @ Wh), 16 batch rows per WG ----
// 8 WGs x 512 thr (8 waves); wave w owns cols [32w, 32w+32) (2 N-tiles).
// Wh B-fragments VGPR-resident (64 VGPRs). h tile [16][256] bf16 in LDS,
// XOR-swizzled (byte ^= (row&7)<<4) to break the 512B-stride bank conflict.
// xp loads double-buffered in registers (issued one step ahead).
__global__ __launch_bounds__(512) void k_scan(const float* __restrict__ xp,
                                              const unsigned short* __restrict__ WhT,
                                              unsigned short* __restrict__ hseq,
                                              float* __restrict__ out) {
  __shared__ unsigned short hbuf[16 * 256];  // 8KB
  const int tid = threadIdx.x;
  const int wave = tid >> 6, lane = tid & 63;
  const int lo = lane & 15, hi = lane >> 4;
  const int wg = blockIdx.x;            // batch rows wg*16 .. wg*16+15
  const int n0 = wave * 32 + lo;        // nt=0 col; nt=1 col = n0+16
  const int rm0 = hi * 4;               // D rows rm0..rm0+3

  // preload this wave's Wh fragments into registers
  bf16x8 bw0[8], bw1[8];
#pragma unroll
  for (int kt = 0; kt < 8; ++kt) {
    bw0[kt] = *(const bf16x8*)(WhT + (size_t)n0 * 256 + kt * 32 + hi * 8);
    bw1[kt] = *(const bf16x8*)(WhT + (size_t)(n0 + 16) * 256 + kt * 32 + hi * 8);
  }
  {
    unsigned int* hb32 = (unsigned int*)hbuf;
    for (int i = tid; i < 2048; i += 512) hb32[i] = 0;  // h0 = 0
  }
  __syncthreads();

  float xva[2][4], xvb[2][4];
#pragma unroll
  for (int nt = 0; nt < 2; ++nt)
#pragma unroll
    for (int j = 0; j < 4; ++j)
      xva[nt][j] = xp[((size_t)(wg * 16 + rm0 + j) * T_ + 0) * 256 + n0 + nt * 16];

  auto step = [&](int t, float (&xv)[2][4], float (&xn)[2][4], int tn) {
    // issue next step's xp loads (latency hidden under this step's compute)
#pragma unroll
    for (int nt = 0; nt < 2; ++nt)
#pragma unroll
      for (int j = 0; j < 4; ++j)
        xn[nt][j] = xp[((size_t)(wg * 16 + rm0 + j) * T_ + tn) * 256 + n0 + nt * 16];
    // A-fragments of h from LDS (swizzled)
    bf16x8 a[8];
#pragma unroll
    for (int kt = 0; kt < 8; ++kt) {
      int byte = lo * 512 + (kt * 32 + hi * 8) * 2;
      byte ^= (lo & 7) << 4;
      a[kt] = *(const bf16x8*)((const char*)hbuf + byte);
    }
    f32x4 acc0 = {xv[0][0], xv[0][1], xv[0][2], xv[0][3]};
    f32x4 acc1 = {xv[1][0], xv[1][1], xv[1][2], xv[1][3]};
#pragma unroll
    for (int kt = 0; kt < 8; ++kt) {
      acc0 = __builtin_amdgcn_mfma_f32_16x16x32_bf16(a[kt], bw0[kt], acc0, 0, 0, 0);
      acc1 = __builtin_amdgcn_mfma_f32_16x16x32_bf16(a[kt], bw1[kt], acc1, 0, 0, 0);
    }
    float th[2][4];
    unsigned short hv[2][4];
#pragma unroll
    for (int j = 0; j < 4; ++j) {
      th[0][j] = tanh_fast(acc0[j]); hv[0][j] = f2bf(th[0][j]);
      th[1][j] = tanh_fast(acc1[j]); hv[1][j] = f2bf(th[1][j]);
    }
    __syncthreads();  // all A-reads of this step done before overwriting h
#pragma unroll
    for (int nt = 0; nt < 2; ++nt)
#pragma unroll
      for (int j = 0; j < 4; ++j) {
        int rm = rm0 + j;
        int byte = (rm * 512 + (n0 + nt * 16) * 2) ^ ((rm & 7) << 4);
        *(unsigned short*)((char*)hbuf + byte) = hv[nt][j];
      }
    if (hseq) {
#pragma unroll
      for (int nt = 0; nt < 2; ++nt)
#pragma unroll
        for (int j = 0; j < 4; ++j)
          hseq[((size_t)(wg * 16 + rm0 + j) * T_ + t) * 256 + n0 + nt * 16] = hv[nt][j];
    }
    if (out && t == T_ - 1) {
#pragma unroll
      for (int nt = 0; nt < 2; ++nt)
#pragma unroll
        for (int j = 0; j < 4; ++j)
          out[(size_t)(wg * 16 + rm0 + j) * 256 + n0 + nt * 16] = th[nt][j];
    }
    __syncthreads();  // h writes visible before next step's reads
  };

  for (int t = 0; t < T_; t += 2) {
    step(t, xva, xvb, t + 1);
    step(t + 1, xvb, xva, (t + 2 < T_) ? (t + 2) : (T_ - 1));
  }
}

extern "C" void kernel_launch(void* const* d_in, const int* in_sizes, int n_in,
                              void* d_out, int out_size, void* d_ws, size_t ws_size,
                              hipStream_t stream) {
  const float* x      = (const float*)d_in[0];
  const float* enc_Wx = (const float*)d_in[1];
  const float* enc_Wh = (const float*)d_in[2];
  const float* enc_b  = (const float*)d_in[3];
  const float* dec_Wx = (const float*)d_in[4];
  const float* dec_Wh = (const float*)d_in[5];
  const float* dec_b  = (const float*)d_in[6];

  char* ws = (char*)d_ws;
  unsigned short* xbf  = (unsigned short*)ws;                          // 64MB  bf16 x
  float*          xpb  = (float*)(ws + ((size_t)64 << 20));            // 128MB xp (enc, then reused for dec)
  unsigned short* hseq = (unsigned short*)(ws + ((size_t)192 << 20));  // 64MB  bf16 h_seq
  unsigned short* wxT  = (unsigned short*)(ws + ((size_t)256 << 20));  // 4 x 128KB transposed bf16 weights
  unsigned short* whT  = wxT + 65536;
  unsigned short* dxT  = wxT + 131072;
  unsigned short* dhT  = wxT + 196608;

  k_cvt_x<<<32768, 256, 0, stream>>>(x, xbf, 8388608);
  k_cvt_t<<<256, 256, 0, stream>>>(enc_Wx, wxT);
  k_cvt_t<<<256, 256, 0, stream>>>(enc_Wh, whT);
  k_cvt_t<<<256, 256, 0, stream>>>(dec_Wx, dxT);
  k_cvt_t<<<256, 256, 0, stream>>>(dec_Wh, dhT);

  // xp_enc = x @ enc_Wx + enc_b
  k_gemm<<<8192, 256, 0, stream>>>(xbf, wxT, enc_b, xpb, 131072);
  // encoder scan -> h_seq (bf16)
  k_scan<<<8, 512, 0, stream>>>(xpb, whT, hseq, nullptr);
  // xp_dec = h_seq @ dec_Wx + dec_b (reuse xp buffer)
  k_gemm<<<8192, 256, 0, stream>>>(hseq, dxT, dec_b, xpb, 131072);
  // decoder scan -> final h to d_out (fp32)
  k_scan<<<8, 512, 0, stream>>>(xpb, dhT, nullptr, (float*)d_out);
}

// Round 2
// 2450.020 us; speedup vs baseline: 1.0758x; 1.0758x over previous
//
#include <hip/hip_runtime.h>

typedef __attribute__((ext_vector_type(8))) short bf16x8;
typedef __attribute__((ext_vector_type(4))) float f32x4;

#define T_ 1024

// round-to-nearest-even f32 -> bf16 bits
__device__ __forceinline__ unsigned short f2bf(float f) {
  unsigned int u = __float_as_uint(f);
  u += 0x7fffu + ((u >> 16) & 1u);
  return (unsigned short)(u >> 16);
}

// tanh(x) = 1 - 2/(1+e^{2x}); saturates cleanly to +-1, no NaN for finite x
__device__ __forceinline__ float tanh_fast(float x) {
  float e = __expf(2.0f * x);
  return 1.0f - __fdividef(2.0f, 1.0f + e);
}

// ---- 4 weight matrices [256][256] f32 -> transposed bf16 [u][f], packed at d + w*65536 ----
__global__ __launch_bounds__(256) void k_cvt_w(const float* __restrict__ s0,
                                               const float* __restrict__ s1,
                                               const float* __restrict__ s2,
                                               const float* __restrict__ s3,
                                               unsigned short* __restrict__ d) {
  int w = blockIdx.x >> 8, f = blockIdx.x & 255, u = threadIdx.x;
  const float* s = w == 0 ? s0 : w == 1 ? s1 : w == 2 ? s2 : s3;
  d[w * 65536 + u * 256 + f] = f2bf(s[f * 256 + u]);
}

// ---- C[M x 256] = A(f32,[M x 256] converted inline) @ B(via Bt bf16 [256][256]) + bias ----
// WG = 256 thr (4 waves), one 16-row M-tile per WG, wave w covers cols [64w, 64w+64)
__global__ __launch_bounds__(256) void k_gemm_x(const float* __restrict__ A,
                                                const unsigned short* __restrict__ Bt,
                                                const float* __restrict__ bias,
                                                float* __restrict__ C) {
  const int wave = threadIdx.x >> 6, lane = threadIdx.x & 63;
  const int lo = lane & 15, hi = lane >> 4;
  const size_t mt = blockIdx.x;
  const float* Ap = A + (mt * 16 + lo) * 256 + hi * 8;
  bf16x8 a[8];
#pragma unroll
  for (int kt = 0; kt < 8; ++kt) {
    float4 u = *(const float4*)(Ap + kt * 32);
    float4 v = *(const float4*)(Ap + kt * 32 + 4);
    bf16x8 r;
    r[0] = (short)f2bf(u.x); r[1] = (short)f2bf(u.y);
    r[2] = (short)f2bf(u.z); r[3] = (short)f2bf(u.w);
    r[4] = (short)f2bf(v.x); r[5] = (short)f2bf(v.y);
    r[6] = (short)f2bf(v.z); r[7] = (short)f2bf(v.w);
    a[kt] = r;
  }
#pragma unroll
  for (int nt = 0; nt < 4; ++nt) {
    const int n = wave * 64 + nt * 16 + lo;
    const unsigned short* Bp = Bt + (size_t)n * 256 + hi * 8;
    const float bv = bias[n];
    f32x4 acc = {bv, bv, bv, bv};
#pragma unroll
    for (int kt = 0; kt < 8; ++kt) {
      bf16x8 b = *(const bf16x8*)(Bp + kt * 32);
      acc = __builtin_amdgcn_mfma_f32_16x16x32_bf16(a[kt], b, acc, 0, 0, 0);
    }
    float* Cp = C + (mt * 16 + hi * 4) * 256 + n;
#pragma unroll
    for (int j = 0; j < 4; ++j) Cp[j * 256] = acc[j];
  }
}

// ---- recurrent scan: h_t = tanh(xp[b,t,:] + h_{t-1} @ Wh) ----
// 8 WGs x 512 thr (8 waves); WG owns 16 batch rows; wave w owns cols [32w,32w+32).
// Wh (and, if FUSE, proj-W) B-fragments VGPR-resident. h tile double-buffered in LDS
// (2 x 8KB, parity via compile-time offset), XOR-swizzled (applied AFTER the full
// byte-address sum). ONE raw barrier per step (lgkmcnt only -- no vmcnt drain, so
// the distance-2 xp prefetch and the proj stores stay in flight across steps).
// FUSE=1 (encoder): also computes xq[t-1] = h_{t-1} @ WpT + pbias (decoder's xp).
// FUSE=0 (decoder): writes final tanh (fp32) for t==T-1 to xq ([128][256]).
template <bool FUSE>
__global__ __launch_bounds__(512, 2) void k_scan(const float* __restrict__ xp,
                                                 const unsigned short* __restrict__ WhT,
                                                 const unsigned short* __restrict__ WpT,
                                                 const float* __restrict__ pbias,
                                                 float* __restrict__ xq) {
  __shared__ char hb[16384];  // [2][16][256] bf16
  const int tid = threadIdx.x, wave = tid >> 6, lane = tid & 63;
  const int lo = lane & 15, hi = lane >> 4;
  const int n0 = wave * 32 + lo;  // cols n0, n0+16
  const int rm0 = hi * 4;         // D rows rm0..rm0+3
  const int wg = blockIdx.x;

  // reg-resident B-fragments
  bf16x8 bh0[8], bh1[8], bp0[8], bp1[8];
#pragma unroll
  for (int kt = 0; kt < 8; ++kt) {
    bh0[kt] = *(const bf16x8*)(WhT + (size_t)n0 * 256 + kt * 32 + hi * 8);
    bh1[kt] = *(const bf16x8*)(WhT + (size_t)(n0 + 16) * 256 + kt * 32 + hi * 8);
    if (FUSE) {
      bp0[kt] = *(const bf16x8*)(WpT + (size_t)n0 * 256 + kt * 32 + hi * 8);
      bp1[kt] = *(const bf16x8*)(WpT + (size_t)(n0 + 16) * 256 + kt * 32 + hi * 8);
    }
  }
  float pb0 = 0.f, pb1 = 0.f;
  if (FUSE) { pb0 = pbias[n0]; pb1 = pbias[n0 + 16]; }

  // zero buf1 (read at t=0) -> h0 = 0
  for (int i = tid; i < 2048; i += 512) ((unsigned int*)(hb + 8192))[i] = 0;
  __syncthreads();

  // per-thread element offsets into xp/xq rows (uniform part goes in the pointer)
  int ofs[4];
#pragma unroll
  for (int j = 0; j < 4; ++j) ofs[j] = (rm0 + j) * T_ * 256 + n0;
  const float* xpw = xp + (size_t)wg * 16 * T_ * 256;
  float* xqw = FUSE ? (xq + (size_t)wg * 16 * T_ * 256) : nullptr;

  // LDS byte addrs, XOR swizzle applied after the full sum (step-invariant)
  const int swz = (lo & 7) << 4;
  int raddr[8], woff[8];
#pragma unroll
  for (int kt = 0; kt < 8; ++kt)
    raddr[kt] = (lo * 512 + kt * 64 + hi * 16) ^ swz;
#pragma unroll
  for (int nt = 0; nt < 2; ++nt)
#pragma unroll
    for (int j = 0; j < 4; ++j) {
      int row = rm0 + j, col = n0 + nt * 16;
      woff[nt * 4 + j] = (row * 512 + col * 2) ^ ((row & 7) << 4);
    }

  // prefetch t=0 and t=1 (distance-2 pipeline, consume-then-refill per parity)
  float xva[8], xvb[8];
#pragma unroll
  for (int q = 0; q < 8; ++q) xva[q] = xpw[ofs[q & 3] + (q >> 2) * 16];
#pragma unroll
  for (int q = 0; q < 8; ++q) xvb[q] = xpw[256 + ofs[q & 3] + (q >> 2) * 16];

  auto step = [&](int t, float (&xv)[8], int roff, int wo) {
    // A-fragments of h_{t-1}
    bf16x8 a[8];
#pragma unroll
    for (int kt = 0; kt < 8; ++kt)
      a[kt] = *(const bf16x8*)(hb + roff + raddr[kt]);
    if (FUSE) {
      if (t > 0) {  // uniform branch: proj of h_{t-1} -> xq[t-1]
        f32x4 p0 = {pb0, pb0, pb0, pb0}, p1 = {pb1, pb1, pb1, pb1};
#pragma unroll
        for (int kt = 0; kt < 8; ++kt) {
          p0 = __builtin_amdgcn_mfma_f32_16x16x32_bf16(a[kt], bp0[kt], p0, 0, 0, 0);
          p1 = __builtin_amdgcn_mfma_f32_16x16x32_bf16(a[kt], bp1[kt], p1, 0, 0, 0);
        }
        float* q_t = xqw + (size_t)(t - 1) * 256;
#pragma unroll
        for (int j = 0; j < 4; ++j) {
          q_t[ofs[j]] = p0[j];
          q_t[ofs[j] + 16] = p1[j];
        }
      }
    }
    // recurrence
    f32x4 c0 = {xv[0], xv[1], xv[2], xv[3]}, c1 = {xv[4], xv[5], xv[6], xv[7]};
#pragma unroll
    for (int kt = 0; kt < 8; ++kt) {
      c0 = __builtin_amdgcn_mfma_f32_16x16x32_bf16(a[kt], bh0[kt], c0, 0, 0, 0);
      c1 = __builtin_amdgcn_mfma_f32_16x16x32_bf16(a[kt], bh1[kt], c1, 0, 0, 0);
    }
    // refill this parity's regs for t+2 (in flight across ~2 steps; no vmcnt drain)
    {
      const int tn = (t + 2 <= T_ - 1) ? t + 2 : T_ - 1;
      const float* p_t = xpw + (size_t)tn * 256;
#pragma unroll
      for (int q = 0; q < 8; ++q) xv[q] = p_t[ofs[q & 3] + (q >> 2) * 16];
    }
    float th[8];
#pragma unroll
    for (int q = 0; q < 8; ++q) th[q] = tanh_fast(q < 4 ? c0[q & 3] : c1[q & 3]);
    if (!FUSE) {
      if (t == T_ - 1) {  // final hidden state, fp32
        float* op = xq + (size_t)wg * 16 * 256;
#pragma unroll
        for (int q = 0; q < 8; ++q)
          op[(rm0 + (q & 3)) * 256 + n0 + (q >> 2) * 16] = th[q];
      }
    }
#pragma unroll
    for (int q = 0; q < 8; ++q)
      *(unsigned short*)(hb + wo + woff[q]) = f2bf(th[q]);
    // LDS writes visible, then barrier. NO vmcnt drain (loads/stores stay in flight).
    asm volatile("s_waitcnt lgkmcnt(0)\n\ts_barrier" ::: "memory");
  };

  for (int t = 0; t < T_; t += 2) {
    step(t, xva, 8192, 0);      // even: read buf1, write buf0
    step(t + 1, xvb, 0, 8192);  // odd:  read buf0, write buf1
  }
  if (FUSE) {  // epilogue: proj of h_{T-1} -> xq[T-1]
    bf16x8 a[8];
#pragma unroll
    for (int kt = 0; kt < 8; ++kt)
      a[kt] = *(const bf16x8*)(hb + 8192 + raddr[kt]);
    f32x4 p0 = {pb0, pb0, pb0, pb0}, p1 = {pb1, pb1, pb1, pb1};
#pragma unroll
    for (int kt = 0; kt < 8; ++kt) {
      p0 = __builtin_amdgcn_mfma_f32_16x16x32_bf16(a[kt], bp0[kt], p0, 0, 0, 0);
      p1 = __builtin_amdgcn_mfma_f32_16x16x32_bf16(a[kt], bp1[kt], p1, 0, 0, 0);
    }
    float* q_t = xqw + (size_t)(T_ - 1) * 256;
#pragma unroll
    for (int j = 0; j < 4; ++j) {
      q_t[ofs[j]] = p0[j];
      q_t[ofs[j] + 16] = p1[j];
    }
  }
}

extern "C" void kernel_launch(void* const* d_in, const int* in_sizes, int n_in,
                              void* d_out, int out_size, void* d_ws, size_t ws_size,
                              hipStream_t stream) {
  const float* x      = (const float*)d_in[0];
  const float* enc_Wx = (const float*)d_in[1];
  const float* enc_Wh = (const float*)d_in[2];
  const float* enc_b  = (const float*)d_in[3];
  const float* dec_Wx = (const float*)d_in[4];
  const float* dec_Wh = (const float*)d_in[5];
  const float* dec_b  = (const float*)d_in[6];

  char* ws = (char*)d_ws;
  float*          xpe = (float*)ws;                                  // 128MB xp_enc
  float*          xpd = (float*)(ws + ((size_t)128 << 20));          // 128MB xp_dec
  unsigned short* wT  = (unsigned short*)(ws + ((size_t)256 << 20)); // 4 x 128KB bf16 W^T

  // wT layout: [0]=enc_Wx^T  [1]=enc_Wh^T  [2]=dec_Wx^T  [3]=dec_Wh^T
  k_cvt_w<<<1024, 256, 0, stream>>>(enc_Wx, enc_Wh, dec_Wx, dec_Wh, wT);
  // xp_enc = x @ enc_Wx + enc_b   (f32 A converted inline)
  k_gemm_x<<<8192, 256, 0, stream>>>(x, wT, enc_b, xpe);
  // encoder scan (fused: also emits xp_dec = h_seq @ dec_Wx + dec_b)
  k_scan<true><<<8, 512, 0, stream>>>(xpe, wT + 65536, wT + 131072, dec_b, xpd);
  // decoder scan -> final hidden state to d_out
  k_scan<false><<<8, 512, 0, stream>>>(xpd, wT + 196608, nullptr, nullptr, (float*)d_out);
}

// Round 3
// 1740.114 us; speedup vs baseline: 1.5147x; 1.4080x over previous
//
#include <hip/hip_runtime.h>

typedef __attribute__((ext_vector_type(8))) short bf16x8;
typedef __attribute__((ext_vector_type(4))) float f32x4;

#define T_ 1024

// round-to-nearest-even f32 -> bf16 bits
__device__ __forceinline__ unsigned short f2bf(float f) {
  unsigned int u = __float_as_uint(f);
  u += 0x7fffu + ((u >> 16) & 1u);
  return (unsigned short)(u >> 16);
}

// tanh(x) = 1 - 2*rcp(1 + exp2(x * 2/ln2)); saturates to +-1, no NaN for finite x
__device__ __forceinline__ float tanh_fast(float x) {
  float e = __builtin_amdgcn_exp2f(x * 2.8853900817779268f);
  return __builtin_fmaf(-2.0f, __builtin_amdgcn_rcpf(1.0f + e), 1.0f);
}

// ---- 4 weight matrices [256][256] f32 -> transposed bf16 [u][f], packed at d + w*65536 ----
__global__ __launch_bounds__(256) void k_cvt_w(const float* __restrict__ s0,
                                               const float* __restrict__ s1,
                                               const float* __restrict__ s2,
                                               const float* __restrict__ s3,
                                               unsigned short* __restrict__ d) {
  int w = blockIdx.x >> 8, f = blockIdx.x & 255, u = threadIdx.x;
  const float* s = w == 0 ? s0 : w == 1 ? s1 : w == 2 ? s2 : s3;
  d[w * 65536 + u * 256 + f] = f2bf(s[f * 256 + u]);
}

// ---- C[M x 256] = A(f32,[M x 256] converted inline) @ B(via Bt bf16 [256][256]) + bias ----
__global__ __launch_bounds__(256) void k_gemm_x(const float* __restrict__ A,
                                                const unsigned short* __restrict__ Bt,
                                                const float* __restrict__ bias,
                                                float* __restrict__ C) {
  const int wave = threadIdx.x >> 6, lane = threadIdx.x & 63;
  const int lo = lane & 15, hi = lane >> 4;
  const size_t mt = blockIdx.x;
  const float* Ap = A + (mt * 16 + lo) * 256 + hi * 8;
  bf16x8 a[8];
#pragma unroll
  for (int kt = 0; kt < 8; ++kt) {
    float4 u = *(const float4*)(Ap + kt * 32);
    float4 v = *(const float4*)(Ap + kt * 32 + 4);
    bf16x8 r;
    r[0] = (short)f2bf(u.x); r[1] = (short)f2bf(u.y);
    r[2] = (short)f2bf(u.z); r[3] = (short)f2bf(u.w);
    r[4] = (short)f2bf(v.x); r[5] = (short)f2bf(v.y);
    r[6] = (short)f2bf(v.z); r[7] = (short)f2bf(v.w);
    a[kt] = r;
  }
#pragma unroll
  for (int nt = 0; nt < 4; ++nt) {
    const int n = wave * 64 + nt * 16 + lo;
    const unsigned short* Bp = Bt + (size_t)n * 256 + hi * 8;
    const float bv = bias[n];
    f32x4 acc = {bv, bv, bv, bv};
#pragma unroll
    for (int kt = 0; kt < 8; ++kt) {
      bf16x8 b = *(const bf16x8*)(Bp + kt * 32);
      acc = __builtin_amdgcn_mfma_f32_16x16x32_bf16(a[kt], b, acc, 0, 0, 0);
    }
    float* Cp = C + (mt * 16 + hi * 4) * 256 + n;
#pragma unroll
    for (int j = 0; j < 4; ++j) Cp[j * 256] = acc[j];
  }
}

// ---- recurrent scan, SWAPPED operands: D[n][b] = sum_k WhT[n][k] * h[b][k] ----
// 8 WGs x 512 thr (8 waves, 2/SIMD); WG owns 16 batch rows (= MFMA B-cols, exact fit);
// wave owns n in [32w, 32w+32) (2 M-tiles). Weights (A-frags) VGPR-resident.
// h tile [16 b][256 k] bf16 in LDS, double-buffered, XOR-swizzled (2-way free per phase).
// D gives each lane (b = lane&15, 4 consecutive n) -> float4 xp loads, b64 LDS writes,
// float4 proj stores. One raw barrier per step (lgkmcnt only, no vmcnt drain).
// FUSE=1 (encoder): also emits xq[t-1] = h_{t-1} @ WpT + pbias (the decoder's xp).
// FUSE=0 (decoder): writes final tanh (fp32) for t==T-1 to xq ([128][256]).
template <bool FUSE>
__global__ __launch_bounds__(512, 2) void k_scan(const float* __restrict__ xp,
                                                 const unsigned short* __restrict__ WhT,
                                                 const unsigned short* __restrict__ WpT,
                                                 const float* __restrict__ pbias,
                                                 float* __restrict__ xq) {
  __shared__ __align__(16) char hb[16384];  // [2][16 b][256 k] bf16
  const int tid = threadIdx.x, wave = tid >> 6, lane = tid & 63;
  const int lo = lane & 15, hi = lane >> 4;
  const int wg = blockIdx.x;
  const int n0 = wave * 32;  // wave's n-range [n0, n0+32)

  // A-frags (weights), VGPR-resident: row n = n0 + nt*16 + lo, k = kt*32 + hi*8 + j
  bf16x8 ah[2][8], ap[2][8];
#pragma unroll
  for (int nt = 0; nt < 2; ++nt)
#pragma unroll
    for (int kt = 0; kt < 8; ++kt) {
      const size_t n = n0 + nt * 16 + lo;
      ah[nt][kt] = *(const bf16x8*)(WhT + n * 256 + kt * 32 + hi * 8);
      if (FUSE) ap[nt][kt] = *(const bf16x8*)(WpT + n * 256 + kt * 32 + hi * 8);
    }
  f32x4 pbv[2] = {{0, 0, 0, 0}, {0, 0, 0, 0}};
  if (FUSE) {
#pragma unroll
    for (int nt = 0; nt < 2; ++nt)
      pbv[nt] = *(const f32x4*)(pbias + n0 + nt * 16 + hi * 4);
  }

  // zero both h buffers (t=0 reads zeros = h0)
  for (int i = tid; i < 4096; i += 512) ((unsigned int*)hb)[i] = 0;
  __syncthreads();

  // LDS byte addrs (step-invariant), swizzle bits 4-6; per-phase (16-lane) 2-way only
  const int swz = (lo & 7) << 4;
  int raddr[8];
#pragma unroll
  for (int kt = 0; kt < 8; ++kt) raddr[kt] = (lo * 512 + kt * 64 + hi * 16) ^ swz;
  int waddr[2];
#pragma unroll
  for (int nt = 0; nt < 2; ++nt)
    waddr[nt] = (lo * 512 + (n0 + nt * 16 + hi * 4) * 2) ^ swz;

  // global bases: this thread touches (b = wg*16+lo, n = n0 + hi*4 + nt*16)
  const size_t brow = (size_t)(wg * 16 + lo);
  const float* xpw = xp + brow * T_ * 256 + n0 + hi * 4;
  float* xqw = FUSE ? (xq + brow * T_ * 256 + n0 + hi * 4) : nullptr;

  // distance-2 register prefetch of xp
  f32x4 xva[2], xvb[2];
#pragma unroll
  for (int nt = 0; nt < 2; ++nt) {
    xva[nt] = *(const f32x4*)(xpw + nt * 16);
    xvb[nt] = *(const f32x4*)(xpw + 256 + nt * 16);
  }

  auto step = [&](int t, f32x4 (&xv)[2], int ro, int wo) {
    // B-frags of h_{t-1} (shared across both n-tiles and proj)
    bf16x8 b[8];
#pragma unroll
    for (int kt = 0; kt < 8; ++kt) b[kt] = *(const bf16x8*)(hb + ro + raddr[kt]);
    // recurrence: acc starts at xp (bias already folded in by the xp GEMM)
    f32x4 c0 = xv[0], c1 = xv[1];
#pragma unroll
    for (int kt = 0; kt < 8; ++kt) {
      c0 = __builtin_amdgcn_mfma_f32_16x16x32_bf16(ah[0][kt], b[kt], c0, 0, 0, 0);
      c1 = __builtin_amdgcn_mfma_f32_16x16x32_bf16(ah[1][kt], b[kt], c1, 0, 0, 0);
    }
    if (FUSE) {
      if (t > 0) {  // proj of h_{t-1} -> xq[t-1] (off critical path)
        f32x4 p0 = pbv[0], p1 = pbv[1];
#pragma unroll
        for (int kt = 0; kt < 8; ++kt) {
          p0 = __builtin_amdgcn_mfma_f32_16x16x32_bf16(ap[0][kt], b[kt], p0, 0, 0, 0);
          p1 = __builtin_amdgcn_mfma_f32_16x16x32_bf16(ap[1][kt], b[kt], p1, 0, 0, 0);
        }
        float* q_t = xqw + (size_t)(t - 1) * 256;
        *(f32x4*)(q_t) = p0;
        *(f32x4*)(q_t + 16) = p1;
      }
    }
    // refill this parity for t+2 (stays in flight; no vmcnt drain at barrier)
    {
      const int tn = (t + 2 <= T_ - 1) ? t + 2 : T_ - 1;
#pragma unroll
      for (int nt = 0; nt < 2; ++nt)
        xv[nt] = *(const f32x4*)(xpw + (size_t)tn * 256 + nt * 16);
    }
    float th[8];
#pragma unroll
    for (int q = 0; q < 8; ++q) th[q] = tanh_fast(q < 4 ? c0[q] : c1[q - 4]);
    if (!FUSE) {
      if (t == T_ - 1) {  // final hidden state, fp32 [128][256]
        float* op = xq + brow * 256 + n0 + hi * 4;
        f32x4 o0 = {th[0], th[1], th[2], th[3]};
        f32x4 o1 = {th[4], th[5], th[6], th[7]};
        *(f32x4*)(op) = o0;
        *(f32x4*)(op + 16) = o1;
      }
    }
    // pack 4 bf16 and write h_t (one ds_write_b64 per tile)
#pragma unroll
    for (int nt = 0; nt < 2; ++nt) {
      ushort4 pk;
      pk.x = f2bf(th[nt * 4 + 0]);
      pk.y = f2bf(th[nt * 4 + 1]);
      pk.z = f2bf(th[nt * 4 + 2]);
      pk.w = f2bf(th[nt * 4 + 3]);
      *(ushort4*)(hb + wo + waddr[nt]) = pk;
    }
    // LDS ops drained, then barrier; global loads/stores stay in flight
    asm volatile("s_waitcnt lgkmcnt(0)\n\ts_barrier" ::: "memory");
  };

  for (int t = 0; t < T_; t += 2) {
    step(t, xva, 8192, 0);      // even: read buf1, write buf0
    step(t + 1, xvb, 0, 8192);  // odd:  read buf0, write buf1
  }
  if (FUSE) {  // epilogue: proj of h_{T-1} (sits in buf1) -> xq[T-1]
    bf16x8 b[8];
#pragma unroll
    for (int kt = 0; kt < 8; ++kt) b[kt] = *(const bf16x8*)(hb + 8192 + raddr[kt]);
    f32x4 p0 = pbv[0], p1 = pbv[1];
#pragma unroll
    for (int kt = 0; kt < 8; ++kt) {
      p0 = __builtin_amdgcn_mfma_f32_16x16x32_bf16(ap[0][kt], b[kt], p0, 0, 0, 0);
      p1 = __builtin_amdgcn_mfma_f32_16x16x32_bf16(ap[1][kt], b[kt], p1, 0, 0, 0);
    }
    float* q_t = xqw + (size_t)(T_ - 1) * 256;
    *(f32x4*)(q_t) = p0;
    *(f32x4*)(q_t + 16) = p1;
  }
}

extern "C" void kernel_launch(void* const* d_in, const int* in_sizes, int n_in,
                              void* d_out, int out_size, void* d_ws, size_t ws_size,
                              hipStream_t stream) {
  const float* x      = (const float*)d_in[0];
  const float* enc_Wx = (const float*)d_in[1];
  const float* enc_Wh = (const float*)d_in[2];
  const float* enc_b  = (const float*)d_in[3];
  const float* dec_Wx = (const float*)d_in[4];
  const float* dec_Wh = (const float*)d_in[5];
  const float* dec_b  = (const float*)d_in[6];

  char* ws = (char*)d_ws;
  float*          xpe = (float*)ws;                                  // 128MB xp_enc
  float*          xpd = (float*)(ws + ((size_t)128 << 20));          // 128MB xp_dec
  unsigned short* wT  = (unsigned short*)(ws + ((size_t)256 << 20)); // 4 x 128KB bf16 W^T

  // wT layout: [0]=enc_Wx^T  [1]=enc_Wh^T  [2]=dec_Wx^T  [3]=dec_Wh^T
  k_cvt_w<<<1024, 256, 0, stream>>>(enc_Wx, enc_Wh, dec_Wx, dec_Wh, wT);
  // xp_enc = x @ enc_Wx + enc_b
  k_gemm_x<<<8192, 256, 0, stream>>>(x, wT, enc_b, xpe);
  // encoder scan (fused: also emits xp_dec = h_seq @ dec_Wx + dec_b)
  k_scan<true><<<8, 512, 0, stream>>>(xpe, wT + 65536, wT + 131072, dec_b, xpd);
  // decoder scan -> final hidden state to d_out
  k_scan<false><<<8, 512, 0, stream>>>(xpd, wT + 196608, nullptr, nullptr, (float*)d_out);
}